// Round 18
// baseline (161.976 us; speedup 1.0000x reference)
//
#include <hip/hip_runtime.h>
#include <math.h>

#define T_LEN   16384
#define NBATCH  8
#define NBLK    6
#define TILE    128
#define HALO    63
#define NTHR    512          // 8 waves; each wave owns 32 rows (2 m-tiles)
#define NWAVE   8
#define NROWS   256          // TILE + 2*HALO = 254, padded to 256
#define NTILES  128
#define HS      18           // f16 row stride in dwords (72 B)
#define HBUF    (NROWS * HS) // one h buffer in dwords

// workspace layout (dwords)
#define WS_CONV 0             // [i6][tap3][nt4][lane64][dw4] = 18432
#define WS_SKIP 18432         // [i6][nt2][lane64][dw4]      = 3072
#define WS_FIN  21504         // [nt2][lane64][dw4]          = 512
#define WS_LOG  22016         // 16 floats logits
#define WS_CNT  22032         // 1 uint completion counter
#define PREP_N  22016
#define PREP_TOT 22036

typedef _Float16 half8 __attribute__((ext_vector_type(8)));
typedef __fp16  fp16x2 __attribute__((ext_vector_type(2)));
typedef float f32x4  __attribute__((ext_vector_type(4)));

union HPK { unsigned u; _Float16 h[2]; fp16x2 pk; };
union AFR { uint2 u2[2]; half8 v; };

__device__ __forceinline__ unsigned packh(float a, float b) {   // 1x v_cvt_pkrtz_f16_f32
    HPK r; r.pk = __builtin_amdgcn_cvt_pkrtz(a, b); return r.u;
}
__device__ __forceinline__ float f16a(unsigned p) { HPK r; r.u = p; return (float)r.h[0]; }
__device__ __forceinline__ float f16b(unsigned p) { HPK r; r.u = p; return (float)r.h[1]; }

// tanh(a)*sigmoid(b), overflow-safe, 3 quarter-rate ops (2 exp + 1 rcp)
__device__ __forceinline__ float gated(float a, float b) {
    float ea  = __expf(-2.0f * fabsf(a));      // (0,1]
    float fb  = __expf(-b);
    float num = 1.0f - ea;
    float den = (1.0f + ea) * (1.0f + fb);
    float t   = num * __builtin_amdgcn_rcpf(den);
    return __builtin_copysignf(t, a);
}
__device__ __forceinline__ float relu(float x) { return fmaxf(x, 0.0f); }

#define MFMA(a, b, c) __builtin_amdgcn_mfma_f32_16x16x32_f16((a), (b), (c), 0, 0, 0)

// ---------------- weight prep: fp32 -> f16 B-fragments (permuted cols) ----------------
__global__ void wavenet_prep(const float* __restrict__ wt, const float* __restrict__ wsg,
                             const float* __restrict__ wsk, const float* __restrict__ wfin,
                             unsigned* __restrict__ out)
{
    int id = blockIdx.x * 256 + threadIdx.x;
    if (id >= PREP_TOT) return;
    if (id >= PREP_N) { out[id] = 0u; return; }   // zero logits + counter
    int dw = id & 3, lane = (id >> 2) & 63;
    int g = lane >> 4, nlo = lane & 15;
    int k0 = g * 8 + dw * 2, k1 = k0 + 1;
    float v0, v1;
    if (id < WS_SKIP) {
        int nt = (id >> 8) & 3; int q = id >> 10;
        int tap = q % 3, i = q / 3;
        int chan = 2 * nlo + (nt & 1);
        const float* src = (nt < 2) ? wt : wsg;
        v0 = src[((i * 3 + tap) * 32 + k0) * 32 + chan];
        v1 = src[((i * 3 + tap) * 32 + k1) * 32 + chan];
    } else if (id < WS_FIN) {
        int t = id - WS_SKIP;
        int nt = (t >> 8) & 1; int i = t >> 9;
        int chan = 2 * nlo + nt;
        v0 = wsk[(i * 32 + k0) * 32 + chan];
        v1 = wsk[(i * 32 + k1) * 32 + chan];
    } else {
        int t = id - WS_FIN;
        int nt = (t >> 8) & 1;
        int chan = 2 * nlo + nt;
        v0 = wfin[k0 * 32 + chan];
        v1 = wfin[k1 * 32 + chan];
    }
    HPK r; r.h[0] = (_Float16)v0; r.h[1] = (_Float16)v1;   // RNE for weights
    out[id] = r.u;
}

// ---------------- main fused kernel ----------------
// (512,8): cap 64 unified regs/wave. Feasible ONLY because the per-m conv
// split (r17) keeps natural demand at ~56 (40 arch + 16 acc AGPR). LDS 40.5KB
// -> 4 blocks/CU; grid 1024 = 4 x 256 CUs -> 32 waves/CU (HW max).
// Spill check = WRITE_SIZE (r13: same geometry at demand ~92 -> 115MB scratch).
__global__ __launch_bounds__(NTHR, 8)
void wavenet_main(const float* __restrict__ x,
                  const float* __restrict__ w_init, const float* __restrict__ b_init,
                  const float* __restrict__ b_tanh, const float* __restrict__ b_sig,
                  const float* __restrict__ b_skip, const float* __restrict__ b_final,
                  const float* __restrict__ b_dense,
                  const float* __restrict__ w_dense,
                  const unsigned* __restrict__ wsB,
                  float* __restrict__ logits, unsigned* __restrict__ counter,
                  float* __restrict__ out)
{
    __shared__ unsigned h_pack[2 * HBUF];      // double-buffered, 36864 B
    __shared__ float x_s[NROWS];               // 1024 B
    __shared__ float bias_s[3 * NBLK * 32];    // [t/s/k][i][ch], 2304 B
    __shared__ float wib_s[64];                // w_init[0..31], b_init[0..31]
    __shared__ float red[NWAVE][2];

    const int tid  = threadIdx.x;
    const int lane = tid & 63;
    const int wv   = tid >> 6;               // 0..7; wave owns rows [wv*32, wv*32+32)
    const int tile = blockIdx.x & (NTILES - 1);
    const int b    = blockIdx.x >> 7;
    const int col0 = lane & 15;
    const int g4   = lane >> 4;

    // ---- stage biases + init weights into LDS (once; loop, 512 < 640 entries) ----
    for (int t = tid; t < 3 * NBLK * 32 + 64; t += NTHR) {
        if (t < 3 * NBLK * 32) {
            int which = t / (NBLK * 32), r = t % (NBLK * 32);
            bias_s[t] = (which == 0) ? b_tanh[r] : (which == 1) ? b_sig[r] : b_skip[r];
        } else {
            int r = t - 3 * NBLK * 32;
            wib_s[r] = (r < 32) ? w_init[r] : b_init[r - 32];
        }
    }

    // ---- init conv (CIN=1) -> f16 h in buf0; 2 threads per row ----
    {
        int j    = tid >> 1;                 // row 0..255
        int half = tid & 1;                  // dwords half*8 .. half*8+7
        int tg = tile * TILE - HALO + j;
        bool valid = (tg >= 0) && (tg < T_LEN);
        float xv = valid ? x[(size_t)b * T_LEN + tg] : 0.0f;
        x_s[j] = xv;                         // both halves write same value (benign)
        unsigned* hp = &h_pack[j * HS + half * 8];
        #pragma unroll
        for (int q = 0; q < 4; ++q) {
            int ch = (half * 8 + 2 * q) * 2; // first of 4 consecutive channels
            float f0 = relu(fmaf(xv, w_init[ch],     b_init[ch]));
            float f1 = relu(fmaf(xv, w_init[ch + 1], b_init[ch + 1]));
            float f2 = relu(fmaf(xv, w_init[ch + 2], b_init[ch + 2]));
            float f3 = relu(fmaf(xv, w_init[ch + 3], b_init[ch + 3]));
            uint2 pk;
            pk.x = valid ? packh(f0, f1) : 0u;
            pk.y = valid ? packh(f2, f3) : 0u;
            *(uint2*)(hp + 2 * q) = pk;
        }
    }
    __syncthreads();

    #pragma unroll
    for (int i = 0; i < NBLK; ++i) {
        const int d = 1 << i;
        const unsigned* cur = &h_pack[(i & 1) * HBUF];
        unsigned*       nxt = &h_pack[((i + 1) & 1) * HBUF];

        // per-m pipeline: conv(m) -> epilogue(m). Conv reads cur only; epilogue
        // writes nxt only (z aliased into own rows, per-wave DS in-order) -> the
        // interleave is hazard-free and only 16 acc AGPRs are ever live.
        #pragma unroll
        for (int m = 0; m < 2; ++m) {
            const int row0 = wv * 32 + 16 * m;

            f32x4 acc[4];
            #pragma unroll
            for (int nt = 0; nt < 4; ++nt) acc[nt] = (f32x4){0.f, 0.f, 0.f, 0.f};

            // conv GEMM: [16 x 96] x [96 x 64], single-product f16
            #pragma unroll
            for (int tap = 0; tap < 3; ++tap) {
                half8 bw[4];
                #pragma unroll
                for (int nt = 0; nt < 4; ++nt)
                    bw[nt] = *(const half8*)(wsB + (((i * 3 + tap) * 4 + nt)) * 256 + lane * 4);
                int r = row0 + (tap - 1) * d + col0;
                r = r < 0 ? 0 : (r > NROWS - 1 ? NROWS - 1 : r);
                const unsigned* hp = cur + r * HS + g4 * 4;
                AFR a; a.u2[0] = *(const uint2*)hp; a.u2[1] = *(const uint2*)(hp + 2);
                #pragma unroll
                for (int nt = 0; nt < 4; ++nt)
                    acc[nt] = MFMA(a.v, bw[nt], acc[nt]);
            }

            // epilogue(m): hold reads + biases issued early, gates, z round trip,
            // skip MFMAs, h update into nxt.
            unsigned hold[4];
            #pragma unroll
            for (int reg = 0; reg < 4; ++reg)
                hold[reg] = cur[(row0 + 4 * g4 + reg) * HS + col0];
            float2 btv = *(const float2*)&bias_s[0 * NBLK * 32 + i * 32 + 2 * col0];
            float2 bsv = *(const float2*)&bias_s[1 * NBLK * 32 + i * 32 + 2 * col0];
            float2 bkv = *(const float2*)&bias_s[2 * NBLK * 32 + i * 32 + 2 * col0];
            half8 skw[2];
            #pragma unroll
            for (int nt = 0; nt < 2; ++nt)
                skw[nt] = *(const half8*)(wsB + WS_SKIP + (i * 2 + nt) * 256 + lane * 4);

            #pragma unroll
            for (int reg = 0; reg < 4; ++reg) {
                float z0 = gated(acc[0][reg] + btv.x, acc[2][reg] + bsv.x);
                float z1 = gated(acc[1][reg] + btv.y, acc[3][reg] + bsv.y);
                nxt[(row0 + 4 * g4 + reg) * HS + col0] = packh(z0, z1);
            }
            asm volatile("s_waitcnt lgkmcnt(0)" ::: "memory");
            const unsigned* za = nxt + (row0 + col0) * HS + g4 * 4;
            AFR az; az.u2[0] = *(const uint2*)za; az.u2[1] = *(const uint2*)(za + 2);
            f32x4 s0 = (f32x4){0.f, 0.f, 0.f, 0.f}, s1 = (f32x4){0.f, 0.f, 0.f, 0.f};
            s0 = MFMA(az.v, skw[0], s0);
            s1 = MFMA(az.v, skw[1], s1);
            #pragma unroll
            for (int reg = 0; reg < 4; ++reg) {
                const int row = row0 + 4 * g4 + reg;
                float sk0 = relu(s0[reg] + bkv.x);
                float sk1 = relu(s1[reg] + bkv.y);
                unsigned ph = hold[reg];
                float h0n = sk0 + f16a(ph);
                float h1n = sk1 + f16b(ph);
                unsigned pk;
                if (i != NBLK - 1) {
                    int tgr = tile * TILE - HALO + row;
                    bool vr = (tgr >= 0) && (tgr < T_LEN);
                    pk = vr ? packh(h0n, h1n) : 0u;
                } else {
                    // y = relu(skip_sum) = relu(h6 - h0), h0 recomputed from x
                    float2 wiv = *(const float2*)&wib_s[2 * col0];
                    float2 biv = *(const float2*)&wib_s[32 + 2 * col0];
                    float xr  = x_s[row];
                    float hi0 = relu(fmaf(xr, wiv.x, biv.x));
                    float hi1 = relu(fmaf(xr, wiv.y, biv.y));
                    pk = packh(relu(h0n - hi0), relu(h1n - hi1));
                }
                nxt[row * HS + col0] = pk;   // own rows only
            }
        }
        __syncthreads();   // ONE barrier per iter: nxt complete for next conv
    }

    // ---- final 1x1 conv via MFMA on y (buf0 after 6 iters; own-wave rows) ----
    const unsigned* ybuf = &h_pack[(NBLK & 1) * HBUF];
    half8 fw[2];
    #pragma unroll
    for (int nt = 0; nt < 2; ++nt)
        fw[nt] = *(const half8*)(wsB + WS_FIN + nt * 256 + lane * 4);
    float2 bfv = *(const float2*)&b_final[2 * col0];
    float pa = 0.0f, pb = 0.0f;

    #pragma unroll
    for (int mt = 0; mt < 2; ++mt) {
        const unsigned* ya = ybuf + (wv * 32 + 16 * mt + col0) * HS + g4 * 4;
        AFR ay; ay.u2[0] = *(const uint2*)ya; ay.u2[1] = *(const uint2*)(ya + 2);
        f32x4 f0 = (f32x4){0.f, 0.f, 0.f, 0.f}, f1 = (f32x4){0.f, 0.f, 0.f, 0.f};
        f0 = MFMA(ay.v, fw[0], f0);
        f1 = MFMA(ay.v, fw[1], f1);
        #pragma unroll
        for (int reg = 0; reg < 4; ++reg) {
            int row = wv * 32 + 16 * mt + 4 * g4 + reg;
            if (row >= HALO && row < HALO + TILE) {
                int tgr = tile * TILE - HALO + row;
                float v0 = relu(f0[reg] + bfv.x);
                float v1 = relu(f1[reg] + bfv.y);
                float4 wd = *(const float4*)&w_dense[((size_t)tgr * 32 + 2 * col0) * 2];
                pa = fmaf(v0, wd.x, pa); pb = fmaf(v0, wd.y, pb);
                pa = fmaf(v1, wd.z, pa); pb = fmaf(v1, wd.w, pb);
            }
        }
    }

    // block reduction -> logits; last-arriving block does the softmax
    #pragma unroll
    for (int off = 32; off > 0; off >>= 1) {
        pa += __shfl_down(pa, off);
        pb += __shfl_down(pb, off);
    }
    if (lane == 0) { red[wv][0] = pa; red[wv][1] = pb; }
    __syncthreads();
    if (tid == 0) {
        float s0 = 0.0f, s1 = 0.0f;
        #pragma unroll
        for (int w = 0; w < NWAVE; ++w) { s0 += red[w][0]; s1 += red[w][1]; }
        atomicAdd(&logits[b * 2 + 0], s0);
        atomicAdd(&logits[b * 2 + 1], s1);
        __threadfence();
        unsigned arrived = atomicAdd(counter, 1u);
        if (arrived == (unsigned)(NBATCH * NTILES - 1)) {
            __threadfence();
            float bd0 = b_dense[0], bd1 = b_dense[1];
            for (int bb = 0; bb < NBATCH; ++bb) {
                float l0 = atomicAdd(&logits[bb * 2 + 0], 0.0f) + bd0;
                float l1 = atomicAdd(&logits[bb * 2 + 1], 0.0f) + bd1;
                float m  = fmaxf(l0, l1);
                float e0 = __expf(l0 - m), e1 = __expf(l1 - m);
                float inv = __builtin_amdgcn_rcpf(e0 + e1);
                out[bb * 2 + 0] = e0 * inv;
                out[bb * 2 + 1] = e1 * inv;
            }
        }
    }
}

extern "C" void kernel_launch(void* const* d_in, const int* in_sizes, int n_in,
                              void* d_out, int out_size, void* d_ws, size_t ws_size,
                              hipStream_t stream) {
    const float* x       = (const float*)d_in[0];
    const float* w_init  = (const float*)d_in[1];
    const float* b_init  = (const float*)d_in[2];
    const float* w_tanh  = (const float*)d_in[3];
    const float* b_tanh  = (const float*)d_in[4];
    const float* w_sig   = (const float*)d_in[5];
    const float* b_sig   = (const float*)d_in[6];
    const float* w_skip  = (const float*)d_in[7];
    const float* b_skip  = (const float*)d_in[8];
    const float* w_final = (const float*)d_in[9];
    const float* b_final = (const float*)d_in[10];
    const float* w_dense = (const float*)d_in[11];
    const float* b_dense = (const float*)d_in[12];

    unsigned* wsB     = (unsigned*)d_ws;
    float*    logits  = (float*)d_ws + WS_LOG;
    unsigned* counter = (unsigned*)d_ws + WS_CNT;

    wavenet_prep<<<(PREP_TOT + 255) / 256, 256, 0, stream>>>(w_tanh, w_sig, w_skip, w_final, wsB);
    wavenet_main<<<NBATCH * NTILES, NTHR, 0, stream>>>(
        x, w_init, b_init, b_tanh, b_sig, b_skip, b_final, b_dense, w_dense,
        wsB, logits, counter, (float*)d_out);
}

// Round 19
// 141.373 us; speedup vs baseline: 1.1457x; 1.1457x over previous
//
#include <hip/hip_runtime.h>
#include <math.h>

#define T_LEN   16384
#define NBATCH  8
#define NBLK    6
#define TILE    256
#define HALO    63
#define NTHR    768          // 12 waves; each wave owns 32 rows (2 m-tiles)
#define NWAVE   12
#define NROWS   384          // TILE + 2*HALO = 382, padded to 384
#define NTILES  64
#define HS      18           // f16 row stride in dwords (72 B)
#define HBUF    (NROWS * HS) // one h buffer in dwords

// workspace layout (dwords)
#define WS_CONV 0             // [i6][tap3][nt4][lane64][dw4] = 18432
#define WS_SKIP 18432         // [i6][nt2][lane64][dw4]      = 3072
#define WS_FIN  21504         // [nt2][lane64][dw4]          = 512
#define WS_LOG  22016         // 16 floats logits
#define WS_CNT  22032         // 1 uint completion counter
#define PREP_N  22016
#define PREP_TOT 22036

typedef _Float16 half8 __attribute__((ext_vector_type(8)));
typedef __fp16  fp16x2 __attribute__((ext_vector_type(2)));
typedef float f32x4  __attribute__((ext_vector_type(4)));

union HPK { unsigned u; _Float16 h[2]; fp16x2 pk; };
union AFR { uint2 u2[2]; half8 v; };

__device__ __forceinline__ unsigned packh(float a, float b) {   // 1x v_cvt_pkrtz_f16_f32
    HPK r; r.pk = __builtin_amdgcn_cvt_pkrtz(a, b); return r.u;
}
__device__ __forceinline__ float f16a(unsigned p) { HPK r; r.u = p; return (float)r.h[0]; }
__device__ __forceinline__ float f16b(unsigned p) { HPK r; r.u = p; return (float)r.h[1]; }

// tanh(a)*sigmoid(b), overflow-safe, 3 quarter-rate ops (2 exp + 1 rcp)
__device__ __forceinline__ float gated(float a, float b) {
    float ea  = __expf(-2.0f * fabsf(a));      // (0,1]
    float fb  = __expf(-b);
    float num = 1.0f - ea;
    float den = (1.0f + ea) * (1.0f + fb);
    float t   = num * __builtin_amdgcn_rcpf(den);
    return __builtin_copysignf(t, a);
}
__device__ __forceinline__ float relu(float x) { return fmaxf(x, 0.0f); }

#define MFMA(a, b, c) __builtin_amdgcn_mfma_f32_16x16x32_f16((a), (b), (c), 0, 0, 0)

// ---------------- weight prep: fp32 -> f16 B-fragments (permuted cols) ----------------
__global__ void wavenet_prep(const float* __restrict__ wt, const float* __restrict__ wsg,
                             const float* __restrict__ wsk, const float* __restrict__ wfin,
                             unsigned* __restrict__ out)
{
    int id = blockIdx.x * 256 + threadIdx.x;
    if (id >= PREP_TOT) return;
    if (id >= PREP_N) { out[id] = 0u; return; }   // zero logits + counter
    int dw = id & 3, lane = (id >> 2) & 63;
    int g = lane >> 4, nlo = lane & 15;
    int k0 = g * 8 + dw * 2, k1 = k0 + 1;
    float v0, v1;
    if (id < WS_SKIP) {
        int nt = (id >> 8) & 3; int q = id >> 10;
        int tap = q % 3, i = q / 3;
        int chan = 2 * nlo + (nt & 1);
        const float* src = (nt < 2) ? wt : wsg;
        v0 = src[((i * 3 + tap) * 32 + k0) * 32 + chan];
        v1 = src[((i * 3 + tap) * 32 + k1) * 32 + chan];
    } else if (id < WS_FIN) {
        int t = id - WS_SKIP;
        int nt = (t >> 8) & 1; int i = t >> 9;
        int chan = 2 * nlo + nt;
        v0 = wsk[(i * 32 + k0) * 32 + chan];
        v1 = wsk[(i * 32 + k1) * 32 + chan];
    } else {
        int t = id - WS_FIN;
        int nt = (t >> 8) & 1;
        int chan = 2 * nlo + nt;
        v0 = wfin[k0 * 32 + chan];
        v1 = wfin[k1 * 32 + chan];
    }
    HPK r; r.h[0] = (_Float16)v0; r.h[1] = (_Float16)v1;   // RNE for weights
    out[id] = r.u;
}

// ---------------- main fused kernel ----------------
// (768,6): cap 85 unified regs/wave -> 6 waves/SIMD -> 2 blocks/CU (24 waves).
// Feasibility comes from the per-m conv split: only 16 AGPR acc live at once.
// Session-verified optimum (r17: 70us main, no spill). Caps of 64 (r13/r18)
// and un-split 32-AGPR acc (r16) both spill -> HBM-bound. Do not re-tighten.
__global__ __launch_bounds__(NTHR, 6)
void wavenet_main(const float* __restrict__ x,
                  const float* __restrict__ w_init, const float* __restrict__ b_init,
                  const float* __restrict__ b_tanh, const float* __restrict__ b_sig,
                  const float* __restrict__ b_skip, const float* __restrict__ b_final,
                  const float* __restrict__ b_dense,
                  const float* __restrict__ w_dense,
                  const unsigned* __restrict__ wsB,
                  float* __restrict__ logits, unsigned* __restrict__ counter,
                  float* __restrict__ out)
{
    __shared__ unsigned h_pack[2 * HBUF];      // double-buffered, 55296 B
    __shared__ float x_s[NROWS];               // 1536 B
    __shared__ float bias_s[3 * NBLK * 32];    // [t/s/k][i][ch], 2304 B
    __shared__ float wib_s[64];                // w_init[0..31], b_init[0..31]
    __shared__ float red[NWAVE][2];

    const int tid  = threadIdx.x;
    const int lane = tid & 63;
    const int wv   = tid >> 6;               // 0..11; wave owns rows [wv*32, wv*32+32)
    const int tile = blockIdx.x & (NTILES - 1);
    const int b    = blockIdx.x >> 6;
    const int col0 = lane & 15;
    const int g4   = lane >> 4;

    // ---- stage biases + init weights into LDS (once) ----
    if (tid < 3 * NBLK * 32) {
        int which = tid / (NBLK * 32), r = tid % (NBLK * 32);
        float v = (which == 0) ? b_tanh[r] : (which == 1) ? b_sig[r] : b_skip[r];
        bias_s[tid] = v;
    } else if (tid < 3 * NBLK * 32 + 64) {
        int r = tid - 3 * NBLK * 32;
        wib_s[r] = (r < 32) ? w_init[r] : b_init[r - 32];
    }

    // ---- init conv (CIN=1) -> f16 h in buf0; 2 threads per row ----
    {
        int j    = tid >> 1;                 // row 0..383
        int half = tid & 1;                  // dwords half*8 .. half*8+7
        int tg = tile * TILE - HALO + j;
        bool valid = (tg >= 0) && (tg < T_LEN);
        float xv = valid ? x[(size_t)b * T_LEN + tg] : 0.0f;
        x_s[j] = xv;                         // both halves write same value (benign)
        unsigned* hp = &h_pack[j * HS + half * 8];
        #pragma unroll
        for (int q = 0; q < 4; ++q) {
            int ch = (half * 8 + 2 * q) * 2; // first of 4 consecutive channels
            float f0 = relu(fmaf(xv, w_init[ch],     b_init[ch]));
            float f1 = relu(fmaf(xv, w_init[ch + 1], b_init[ch + 1]));
            float f2 = relu(fmaf(xv, w_init[ch + 2], b_init[ch + 2]));
            float f3 = relu(fmaf(xv, w_init[ch + 3], b_init[ch + 3]));
            uint2 pk;
            pk.x = valid ? packh(f0, f1) : 0u;
            pk.y = valid ? packh(f2, f3) : 0u;
            *(uint2*)(hp + 2 * q) = pk;
        }
    }
    __syncthreads();

    #pragma unroll
    for (int i = 0; i < NBLK; ++i) {
        const int d = 1 << i;
        const unsigned* cur = &h_pack[(i & 1) * HBUF];
        unsigned*       nxt = &h_pack[((i + 1) & 1) * HBUF];

        // per-m pipeline: conv(m) -> epilogue(m). Conv reads cur only; epilogue
        // writes nxt only (z aliased into own rows, per-wave DS in-order) -> the
        // interleave is hazard-free and only 16 acc AGPRs are ever live.
        #pragma unroll
        for (int m = 0; m < 2; ++m) {
            const int row0 = wv * 32 + 16 * m;

            f32x4 acc[4];
            #pragma unroll
            for (int nt = 0; nt < 4; ++nt) acc[nt] = (f32x4){0.f, 0.f, 0.f, 0.f};

            // conv GEMM: [16 x 96] x [96 x 64], single-product f16
            #pragma unroll
            for (int tap = 0; tap < 3; ++tap) {
                half8 bw[4];
                #pragma unroll
                for (int nt = 0; nt < 4; ++nt)
                    bw[nt] = *(const half8*)(wsB + (((i * 3 + tap) * 4 + nt)) * 256 + lane * 4);
                int r = row0 + (tap - 1) * d + col0;
                r = r < 0 ? 0 : (r > NROWS - 1 ? NROWS - 1 : r);
                const unsigned* hp = cur + r * HS + g4 * 4;
                AFR a; a.u2[0] = *(const uint2*)hp; a.u2[1] = *(const uint2*)(hp + 2);
                #pragma unroll
                for (int nt = 0; nt < 4; ++nt)
                    acc[nt] = MFMA(a.v, bw[nt], acc[nt]);
            }

            // epilogue(m): hold reads + biases issued early, gates, z round trip,
            // skip MFMAs, h update into nxt.
            unsigned hold[4];
            #pragma unroll
            for (int reg = 0; reg < 4; ++reg)
                hold[reg] = cur[(row0 + 4 * g4 + reg) * HS + col0];
            float2 btv = *(const float2*)&bias_s[0 * NBLK * 32 + i * 32 + 2 * col0];
            float2 bsv = *(const float2*)&bias_s[1 * NBLK * 32 + i * 32 + 2 * col0];
            float2 bkv = *(const float2*)&bias_s[2 * NBLK * 32 + i * 32 + 2 * col0];
            half8 skw[2];
            #pragma unroll
            for (int nt = 0; nt < 2; ++nt)
                skw[nt] = *(const half8*)(wsB + WS_SKIP + (i * 2 + nt) * 256 + lane * 4);

            #pragma unroll
            for (int reg = 0; reg < 4; ++reg) {
                float z0 = gated(acc[0][reg] + btv.x, acc[2][reg] + bsv.x);
                float z1 = gated(acc[1][reg] + btv.y, acc[3][reg] + bsv.y);
                nxt[(row0 + 4 * g4 + reg) * HS + col0] = packh(z0, z1);
            }
            asm volatile("s_waitcnt lgkmcnt(0)" ::: "memory");
            const unsigned* za = nxt + (row0 + col0) * HS + g4 * 4;
            AFR az; az.u2[0] = *(const uint2*)za; az.u2[1] = *(const uint2*)(za + 2);
            f32x4 s0 = (f32x4){0.f, 0.f, 0.f, 0.f}, s1 = (f32x4){0.f, 0.f, 0.f, 0.f};
            s0 = MFMA(az.v, skw[0], s0);
            s1 = MFMA(az.v, skw[1], s1);
            #pragma unroll
            for (int reg = 0; reg < 4; ++reg) {
                const int row = row0 + 4 * g4 + reg;
                float sk0 = relu(s0[reg] + bkv.x);
                float sk1 = relu(s1[reg] + bkv.y);
                unsigned ph = hold[reg];
                float h0n = sk0 + f16a(ph);
                float h1n = sk1 + f16b(ph);
                unsigned pk;
                if (i != NBLK - 1) {
                    int tgr = tile * TILE - HALO + row;
                    bool vr = (tgr >= 0) && (tgr < T_LEN);
                    pk = vr ? packh(h0n, h1n) : 0u;
                } else {
                    // y = relu(skip_sum) = relu(h6 - h0), h0 recomputed from x
                    float2 wiv = *(const float2*)&wib_s[2 * col0];
                    float2 biv = *(const float2*)&wib_s[32 + 2 * col0];
                    float xr  = x_s[row];
                    float hi0 = relu(fmaf(xr, wiv.x, biv.x));
                    float hi1 = relu(fmaf(xr, wiv.y, biv.y));
                    pk = packh(relu(h0n - hi0), relu(h1n - hi1));
                }
                nxt[row * HS + col0] = pk;   // own rows only
            }
        }
        __syncthreads();   // ONE barrier per iter: nxt complete for next conv
    }

    // ---- final 1x1 conv via MFMA on y (buf0 after 6 iters; own-wave rows) ----
    const unsigned* ybuf = &h_pack[(NBLK & 1) * HBUF];
    half8 fw[2];
    #pragma unroll
    for (int nt = 0; nt < 2; ++nt)
        fw[nt] = *(const half8*)(wsB + WS_FIN + nt * 256 + lane * 4);
    float2 bfv = *(const float2*)&b_final[2 * col0];
    float pa = 0.0f, pb = 0.0f;

    #pragma unroll
    for (int mt = 0; mt < 2; ++mt) {
        const unsigned* ya = ybuf + (wv * 32 + 16 * mt + col0) * HS + g4 * 4;
        AFR ay; ay.u2[0] = *(const uint2*)ya; ay.u2[1] = *(const uint2*)(ya + 2);
        f32x4 f0 = (f32x4){0.f, 0.f, 0.f, 0.f}, f1 = (f32x4){0.f, 0.f, 0.f, 0.f};
        f0 = MFMA(ay.v, fw[0], f0);
        f1 = MFMA(ay.v, fw[1], f1);
        #pragma unroll
        for (int reg = 0; reg < 4; ++reg) {
            int row = wv * 32 + 16 * mt + 4 * g4 + reg;
            if (row >= HALO && row < HALO + TILE) {
                int tgr = tile * TILE - HALO + row;
                float v0 = relu(f0[reg] + bfv.x);
                float v1 = relu(f1[reg] + bfv.y);
                float4 wd = *(const float4*)&w_dense[((size_t)tgr * 32 + 2 * col0) * 2];
                pa = fmaf(v0, wd.x, pa); pb = fmaf(v0, wd.y, pb);
                pa = fmaf(v1, wd.z, pa); pb = fmaf(v1, wd.w, pb);
            }
        }
    }

    // block reduction -> logits; last-arriving block does the softmax
    #pragma unroll
    for (int off = 32; off > 0; off >>= 1) {
        pa += __shfl_down(pa, off);
        pb += __shfl_down(pb, off);
    }
    if (lane == 0) { red[wv][0] = pa; red[wv][1] = pb; }
    __syncthreads();
    if (tid == 0) {
        float s0 = 0.0f, s1 = 0.0f;
        #pragma unroll
        for (int w = 0; w < NWAVE; ++w) { s0 += red[w][0]; s1 += red[w][1]; }
        atomicAdd(&logits[b * 2 + 0], s0);
        atomicAdd(&logits[b * 2 + 1], s1);
        __threadfence();
        unsigned arrived = atomicAdd(counter, 1u);
        if (arrived == (unsigned)(NBATCH * NTILES - 1)) {
            __threadfence();
            float bd0 = b_dense[0], bd1 = b_dense[1];
            for (int bb = 0; bb < NBATCH; ++bb) {
                float l0 = atomicAdd(&logits[bb * 2 + 0], 0.0f) + bd0;
                float l1 = atomicAdd(&logits[bb * 2 + 1], 0.0f) + bd1;
                float m  = fmaxf(l0, l1);
                float e0 = __expf(l0 - m), e1 = __expf(l1 - m);
                float inv = __builtin_amdgcn_rcpf(e0 + e1);
                out[bb * 2 + 0] = e0 * inv;
                out[bb * 2 + 1] = e1 * inv;
            }
        }
    }
}

extern "C" void kernel_launch(void* const* d_in, const int* in_sizes, int n_in,
                              void* d_out, int out_size, void* d_ws, size_t ws_size,
                              hipStream_t stream) {
    const float* x       = (const float*)d_in[0];
    const float* w_init  = (const float*)d_in[1];
    const float* b_init  = (const float*)d_in[2];
    const float* w_tanh  = (const float*)d_in[3];
    const float* b_tanh  = (const float*)d_in[4];
    const float* w_sig   = (const float*)d_in[5];
    const float* b_sig   = (const float*)d_in[6];
    const float* w_skip  = (const float*)d_in[7];
    const float* b_skip  = (const float*)d_in[8];
    const float* w_final = (const float*)d_in[9];
    const float* b_final = (const float*)d_in[10];
    const float* w_dense = (const float*)d_in[11];
    const float* b_dense = (const float*)d_in[12];

    unsigned* wsB     = (unsigned*)d_ws;
    float*    logits  = (float*)d_ws + WS_LOG;
    unsigned* counter = (unsigned*)d_ws + WS_CNT;

    wavenet_prep<<<(PREP_TOT + 255) / 256, 256, 0, stream>>>(w_tanh, w_sig, w_skip, w_final, wsB);
    wavenet_main<<<NBATCH * NTILES, NTHR, 0, stream>>>(
        x, w_init, b_init, b_tanh, b_sig, b_skip, b_final, b_dense, w_dense,
        wsB, logits, counter, (float*)d_out);
}